// Round 5
// baseline (13259.435 us; speedup 1.0000x reference)
//
#include <hip/hip_runtime.h>
#include <cstdint>
#include <cstddef>

#define HID 1024
#define INP 512
#define BATCH 128
#define TSTEPS 256
#define NK16 96         // K/16
#define NK16X 32        // x part k16 count
#define NK16H 64        // h part k16 count

using short8  = __attribute__((ext_vector_type(8))) short;
using f32x16  = __attribute__((ext_vector_type(16))) float;

#define LD8(p) (*(const short8*)(p))
#define MFMA32(a,b,c) __builtin_amdgcn_mfma_f32_32x32x16_bf16((a),(b),(c),0,0,0)

static __device__ __forceinline__ unsigned short f2bf(float f) {
    union { float f; unsigned int u; } v; v.f = f;
    unsigned int r = v.u + 0x7fffu + ((v.u >> 16) & 1u);   // RNE
    return (unsigned short)(r >> 16);
}
static __device__ __forceinline__ float bf2f(unsigned short b) {
    union { unsigned int u; float f; } v; v.u = ((unsigned int)b) << 16;
    return v.f;
}
static __device__ __forceinline__ float sigmoid_f(float z) {
    return 1.0f / (1.0f + __expf(-z));
}
static __device__ __forceinline__ float tanh_f(float z) {
    return 2.0f / (1.0f + __expf(-2.0f * z)) - 1.0f;
}

// ---------------------------------------------------------------------------
// Fragment layouts (32x32x16 MFMA, unchanged from round 4 = verified):
//   A: lane l holds W[s*32 + (l&31)][k16*16 + (l>>5)*8 + e]
//      wfrag[s:128][k16:96][p:2][lane:64][e:8]   (p: 0=hi, 1=lo)
//   B: lane l holds act[col = cg*32 + (l&31)][k16*16 + (l>>5)*8 + e]
//      xfrag[t:256][k16:32][cg:4][p:2][lane:64][e:8]
//      hfrag[k16:64][cg:4][p:2][lane:64][e:8]
// ---------------------------------------------------------------------------

// Prep 1: weights -> wfrag. Grid (96, 128) = (k16, s), 256 threads. (round-4)
__global__ void prep_w(const float* __restrict__ Wgx, const float* __restrict__ Wix,
                       const float* __restrict__ Wfx, const float* __restrict__ Wox,
                       const float* __restrict__ Wgh, const float* __restrict__ Wih,
                       const float* __restrict__ Wfh, const float* __restrict__ Woh,
                       unsigned short* __restrict__ wfrag)
{
    const int k16 = blockIdx.x;        // 0..95
    const int s   = blockIdx.y;        // 0..127
    const int tid  = threadIdx.x;
    const int lane = tid >> 2;         // 0..63
    const int e0   = (tid & 3) * 2;    // 0,2,4,6
    const int row  = s * 32 + (lane & 31);
    const int k    = k16 * 16 + (lane >> 5) * 8 + e0;
    const int j = row >> 2;
    const int g = row & 3;
    float f0, f1;
    if (k < INP) {
        const float* wx = (g == 0 ? Wgx : g == 1 ? Wix : g == 2 ? Wfx : Wox) + (size_t)j * INP;
        f0 = wx[k]; f1 = wx[k + 1];
    } else {
        const float* wh = (g == 0 ? Wgh : g == 1 ? Wih : g == 2 ? Wfh : Woh) + (size_t)j * HID;
        f0 = wh[k - INP]; f1 = wh[k - INP + 1];
    }
    ushort2 hi, lo;
    hi.x = f2bf(f0); lo.x = f2bf(f0 - bf2f(hi.x));
    hi.y = f2bf(f1); lo.y = f2bf(f1 - bf2f(hi.y));
    unsigned short* base = wfrag + ((size_t)(s * NK16 + k16) * 2) * 512 + lane * 8 + e0;
    *(ushort2*)(base)       = hi;
    *(ushort2*)(base + 512) = lo;
}

// Prep 2: x -> xfrag. Grid (32, 256) = (k16x, t), 256 threads. (round-4)
__global__ void prep_x(const float* __restrict__ x, unsigned short* __restrict__ xfrag)
{
    const int k16x = blockIdx.x;       // 0..31
    const int t    = blockIdx.y;       // 0..255
    const int tid  = threadIdx.x;
    const int cg   = tid >> 6;         // 0..3
    const int lane = tid & 63;
    const int col  = cg * 32 + (lane & 31);
    const int k0   = k16x * 16 + (lane >> 5) * 8;
    const float* src = x + ((size_t)col * TSTEPS + t) * INP + k0;
    const float4 v0 = *(const float4*)(src);
    const float4 v1 = *(const float4*)(src + 4);
    ushort4 h0, l0, h1, l1;
    h0.x = f2bf(v0.x); l0.x = f2bf(v0.x - bf2f(h0.x));
    h0.y = f2bf(v0.y); l0.y = f2bf(v0.y - bf2f(h0.y));
    h0.z = f2bf(v0.z); l0.z = f2bf(v0.z - bf2f(h0.z));
    h0.w = f2bf(v0.w); l0.w = f2bf(v0.w - bf2f(h0.w));
    h1.x = f2bf(v1.x); l1.x = f2bf(v1.x - bf2f(h1.x));
    h1.y = f2bf(v1.y); l1.y = f2bf(v1.y - bf2f(h1.y));
    h1.z = f2bf(v1.z); l1.z = f2bf(v1.z - bf2f(h1.z));
    h1.w = f2bf(v1.w); l1.w = f2bf(v1.w - bf2f(h1.w));
    unsigned short* base = xfrag +
        ((size_t)(((size_t)t * NK16X + k16x) * 4 + cg) * 2) * 512 + lane * 8;
    *(ushort4*)(base)           = h0;
    *(ushort4*)(base + 4)       = h1;
    *(ushort4*)(base + 512)     = l0;
    *(ushort4*)(base + 512 + 4) = l1;
}

// Prep 3: h0 (H,B) -> hfrag0; zero the grid barrier. 512 blocks x 256.
__global__ void prep_state(const float* __restrict__ hin,
                           unsigned short* __restrict__ hfrag0,
                           unsigned* __restrict__ bar)
{
    const int idx = blockIdx.x * 256 + threadIdx.x;   // 0..131071
    if (idx == 0) { bar[0] = 0u; bar[1] = 0u; }
    const int j = idx >> 7;
    const int b = idx & 127;
    float f = hin[idx];
    unsigned short hh = f2bf(f);
    unsigned short hl = f2bf(f - bf2f(hh));
    const int k16h = j >> 4;
    const int hlf  = (j >> 3) & 1;
    const int e    = j & 7;
    const int cg   = b >> 5;
    const int lane = 32 * hlf + (b & 31);
    unsigned short* base = hfrag0 +
        ((size_t)((k16h * 4 + cg) * 2) * 512) + lane * 8 + e;
    base[0]   = hh;
    base[512] = hl;
}

// ---------------------------------------------------------------------------
// Persistent LSTM: one cooperative kernel runs all 256 timesteps.
// Grid 256 x 512 (8 waves), 1 block/CU. Block (s = bx>>1: 32 gate-rows / 8 j,
// cb = bx&1: 64-col half). bx&7 XCD mapping => each XCD's 32 blocks share one
// cb => B fragments stay XCD-L2-local.
// Wave wv = kq owns k16 set {8*kk + kq} (4 x-chunks + 8 h-chunks, uniform trip
// counts => weight regs statically indexed). Weights: 96 VGPRs/wave, loaded
// once, reused 256 steps. Split-bf16 triple product into 2 acc chains.
// K-partials: two-stage LDS reduction (34 KB). c state: LDS, block-private.
// Steps separated by device-scope generation barrier (cooperative launch
// guarantees co-residency; __threadfence + acquire loads handle cross-XCD L2).
// ---------------------------------------------------------------------------
__global__ __launch_bounds__(512, 2) void lstm_persist(
    const unsigned short* __restrict__ wfrag,
    const unsigned short* __restrict__ xfrag,
    unsigned short* __restrict__ hf0,
    unsigned short* __restrict__ hf1,
    const float* __restrict__ c0,
    const float* __restrict__ bg, const float* __restrict__ bi,
    const float* __restrict__ bf_, const float* __restrict__ bo,
    float* __restrict__ outf,
    unsigned* __restrict__ bar)
{
    const int tid  = threadIdx.x;
    const int wv   = tid >> 6;      // k-slice in K-loop; j-row in epilogue
    const int lane = tid & 63;
    const int l31  = lane & 31;
    const int hl   = lane >> 5;
    const int bx   = blockIdx.x;
    const int s    = bx >> 1;       // rowslice: 32 gate-rows = 8 j
    const int cb   = bx & 1;        // col half

    __shared__ float part[4][32][64];   // 32 KB two-stage partials
    __shared__ float c_lds[8][64];      // c state, block-private

    // ---- weights into registers, once ----
    short8 Wh[12], Wl[12];
    {
        const unsigned short* wb = wfrag + ((size_t)(s * NK16 + wv)) * 1024 + lane * 8;
#pragma unroll
        for (int kk = 0; kk < 12; ++kk) {
            Wh[kk] = LD8(wb);
            Wl[kk] = LD8(wb + 512);
            wb += 8192;                 // 8 k16 slots
        }
    }
    // ---- c into LDS ----
    c_lds[wv][lane] = c0[(size_t)(s * 8 + wv) * 128 + cb * 64 + lane];

    // epilogue constants (thread = (j row wv, col lane))
    const int jq    = s * 8 + wv;
    const float bgv = bg[jq], biv = bi[jq], bfv = bf_[jq], bov = bo[jq];
    const int ecol  = cb * 64 + lane;
    const int ecg   = ecol >> 5;
    const size_t hfoff = ((size_t)((s >> 1) * 4 + ecg) * 2) * 512
                       + ((size_t)((s & 1) * 32 + (lane & 31))) * 8 + wv;
    const size_t xoff = (size_t)wv * 4096 + (size_t)cb * 2048 + (size_t)lane * 8;

    for (int t = 0; t < TSTEPS; ++t) {
        const unsigned short* hin  = (t & 1) ? hf1 : hf0;
        unsigned short*       hout = (t & 1) ? hf0 : hf1;

        f32x16 a0, a1;
#pragma unroll
        for (int r = 0; r < 16; ++r) { a0[r] = 0.f; a1[r] = 0.f; }

        // x part: kg = 8*kk + wv, kk = 0..3
        const unsigned short* px = xfrag + (size_t)t * 131072 + xoff;
#pragma unroll
        for (int kk = 0; kk < 4; ++kk) {
            short8 B0h = LD8(px);
            short8 B0l = LD8(px + 512);
            short8 B1h = LD8(px + 1024);
            short8 B1l = LD8(px + 1536);
            px += 32768;
            a0 = MFMA32(Wh[kk], B0h, a0);
            a1 = MFMA32(Wh[kk], B1h, a1);
            a0 = MFMA32(Wh[kk], B0l, a0);
            a1 = MFMA32(Wh[kk], B1l, a1);
            a0 = MFMA32(Wl[kk], B0h, a0);
            a1 = MFMA32(Wl[kk], B1h, a1);
        }
        // h part: k16h = 8*kk + wv, kk = 0..7
        const unsigned short* ph = hin + xoff;
#pragma unroll
        for (int kk = 0; kk < 8; ++kk) {
            short8 B0h = LD8(ph);
            short8 B0l = LD8(ph + 512);
            short8 B1h = LD8(ph + 1024);
            short8 B1l = LD8(ph + 1536);
            ph += 32768;
            a0 = MFMA32(Wh[4 + kk], B0h, a0);
            a1 = MFMA32(Wh[4 + kk], B1h, a1);
            a0 = MFMA32(Wh[4 + kk], B0l, a0);
            a1 = MFMA32(Wh[4 + kk], B1l, a1);
            a0 = MFMA32(Wl[4 + kk], B0h, a0);
            a1 = MFMA32(Wl[4 + kk], B1h, a1);
        }

        // ---- two-stage k-partial reduction in LDS ----
        // stage A: waves 4..7 dump; stage B: waves 0..3 add theirs and dump.
        // D layout (verified): localrow = (r&3) + 8*(r>>2) + 4*hl, col = l31.
        if (wv >= 4) {
#pragma unroll
            for (int r = 0; r < 16; ++r) {
                const int lr = (r & 3) + 8 * (r >> 2) + 4 * hl;
                part[wv - 4][lr][l31]      = a0[r];
                part[wv - 4][lr][32 + l31] = a1[r];
            }
        }
        __syncthreads();
        if (wv < 4) {
#pragma unroll
            for (int r = 0; r < 16; ++r) {
                const int lr = (r & 3) + 8 * (r >> 2) + 4 * hl;
                part[wv][lr][l31]      += a0[r];
                part[wv][lr][32 + l31] += a1[r];
            }
        }
        __syncthreads();

        // ---- gates: thread (row j = wv, col = lane) ----
        {
            float z0 = 0.f, z1 = 0.f, z2 = 0.f, z3 = 0.f;
#pragma unroll
            for (int p = 0; p < 4; ++p) {
                z0 += part[p][4 * wv + 0][lane];
                z1 += part[p][4 * wv + 1][lane];
                z2 += part[p][4 * wv + 2][lane];
                z3 += part[p][4 * wv + 3][lane];
            }
            float gg = tanh_f(z0 + bgv);
            float ig = sigmoid_f(z1 + biv);
            float fg = sigmoid_f(z2 + bfv);
            float og = sigmoid_f(z3 + bov);
            float cn = gg * ig + c_lds[wv][lane] * fg;
            c_lds[wv][lane] = cn;
            float hh = tanh_f(cn) * og;
            unsigned short hb  = f2bf(hh);
            unsigned short hlo = f2bf(hh - bf2f(hb));
            hout[hfoff]       = hb;
            hout[hfoff + 512] = hlo;
            if (t == TSTEPS - 1) outf[(size_t)jq * BATCH + ecol] = hh;
        }

        // ---- grid barrier (generation counter, device scope) ----
        __syncthreads();                 // drains h stores (vmcnt 0)
        if (tid == 0) {
            __threadfence();             // release: XCD L2 writeback
            unsigned g = __hip_atomic_load(&bar[1], __ATOMIC_RELAXED,
                                           __HIP_MEMORY_SCOPE_AGENT);
            unsigned old = __hip_atomic_fetch_add(&bar[0], 1u, __ATOMIC_ACQ_REL,
                                                  __HIP_MEMORY_SCOPE_AGENT);
            if (old == (unsigned)(gridDim.x - 1)) {
                __hip_atomic_store(&bar[0], 0u, __ATOMIC_RELAXED,
                                   __HIP_MEMORY_SCOPE_AGENT);
                __hip_atomic_fetch_add(&bar[1], 1u, __ATOMIC_RELEASE,
                                       __HIP_MEMORY_SCOPE_AGENT);
            } else {
                while (__hip_atomic_load(&bar[1], __ATOMIC_ACQUIRE,
                                         __HIP_MEMORY_SCOPE_AGENT) == g)
                    __builtin_amdgcn_s_sleep(4);
            }
            __threadfence();             // acquire: invalidate L1/L2
        }
        __syncthreads();
        (void)__hip_atomic_load(&bar[1], __ATOMIC_ACQUIRE,
                                __HIP_MEMORY_SCOPE_AGENT);   // per-thread acquire
    }
}

// ---------------------------------------------------------------------------
extern "C" void kernel_launch(void* const* d_in, const int* in_sizes, int n_in,
                              void* d_out, int out_size, void* d_ws, size_t ws_size,
                              hipStream_t stream)
{
    const float* x   = (const float*)d_in[0];
    const float* c0v = (const float*)d_in[1];
    const float* h0v = (const float*)d_in[2];
    const float* Wgx = (const float*)d_in[3];
    const float* Wix = (const float*)d_in[4];
    const float* Wfx = (const float*)d_in[5];
    const float* Wox = (const float*)d_in[6];
    const float* Wgh = (const float*)d_in[7];
    const float* Wih = (const float*)d_in[8];
    const float* Wfh = (const float*)d_in[9];
    const float* Woh = (const float*)d_in[10];
    const float* bg  = (const float*)d_in[11];
    const float* bi  = (const float*)d_in[12];
    const float* bf  = (const float*)d_in[13];
    const float* bo  = (const float*)d_in[14];

    // ws layout (ushort unless noted): wfrag 25.2 MB, xfrag 67.1 MB,
    // hf0/hf1 0.5 MB each, barrier 8 B. Total ~93.4 MB.
    unsigned short* wfrag = (unsigned short*)d_ws;
    unsigned short* xfrag = wfrag + (size_t)128 * NK16 * 2 * 512;
    unsigned short* hf0   = xfrag + (size_t)TSTEPS * NK16X * 4 * 2 * 512;
    unsigned short* hf1   = hf0 + (size_t)NK16H * 4 * 2 * 512;
    unsigned*       bar   = (unsigned*)(hf1 + (size_t)NK16H * 4 * 2 * 512);

    prep_w<<<dim3(NK16, 128), dim3(256), 0, stream>>>(Wgx, Wix, Wfx, Wox,
                                                      Wgh, Wih, Wfh, Woh, wfrag);
    prep_x<<<dim3(NK16X, TSTEPS), dim3(256), 0, stream>>>(x, xfrag);
    prep_state<<<dim3(512), dim3(256), 0, stream>>>(h0v, hf0, bar);

    float* outp = (float*)d_out;
    void* args[] = { (void*)&wfrag, (void*)&xfrag, (void*)&hf0, (void*)&hf1,
                     (void*)&c0v, (void*)&bg, (void*)&bi, (void*)&bf, (void*)&bo,
                     (void*)&outp, (void*)&bar };
    hipError_t e = hipLaunchCooperativeKernel(
        reinterpret_cast<const void*>(&lstm_persist),
        dim3(256), dim3(512), args, 0, stream);
    if (e != hipSuccess) {
        // Fallback: plain launch. 256 blocks x 1/CU on a 256-CU chip are
        // co-resident in practice; barrier semantics unchanged.
        lstm_persist<<<dim3(256), dim3(512), 0, stream>>>(
            wfrag, xfrag, hf0, hf1, c0v, bg, bi, bf, bo, outp, bar);
    }
}

// Round 6
// 2762.674 us; speedup vs baseline: 4.7995x; 4.7995x over previous
//
#include <hip/hip_runtime.h>
#include <cstdint>
#include <cstddef>

#define HID 1024
#define INP 512
#define BATCH 128
#define TSTEPS 256
#define NK16 96         // K/16 total (x: 0..31, h: 32..95)
#define ZSLOTS 32       // rotating z0 chunk depth (t mod 32)

using short8  = __attribute__((ext_vector_type(8))) short;
using f32x16  = __attribute__((ext_vector_type(16))) float;

#define LD8(p) (*(const short8*)(p))
#define MFMA32(a,b,c) __builtin_amdgcn_mfma_f32_32x32x16_bf16((a),(b),(c),0,0,0)

static __device__ __forceinline__ unsigned short f2bf(float f) {
    union { float f; unsigned int u; } v; v.f = f;
    unsigned int r = v.u + 0x7fffu + ((v.u >> 16) & 1u);   // RNE
    return (unsigned short)(r >> 16);
}
static __device__ __forceinline__ float bf2f(unsigned short b) {
    union { unsigned int u; float f; } v; v.u = ((unsigned int)b) << 16;
    return v.f;
}
static __device__ __forceinline__ float sigmoid_f(float z) {
    return 1.0f / (1.0f + __expf(-z));
}
static __device__ __forceinline__ float tanh_f(float z) {
    return 2.0f / (1.0f + __expf(-2.0f * z)) - 1.0f;
}

// ---------------------------------------------------------------------------
// Fragment layouts (32x32x16 MFMA; verified rounds 4-5):
//   A: lane l holds W[s*32 + (l&31)][k16*16 + (l>>5)*8 + e]
//      wfrag[s:128][k16:96][p:2][lane:64][e:8]   (p: 0=hi, 1=lo)
//   B: lane l holds act[col = cg*32 + (l&31)][k16*16 + (l>>5)*8 + e]
//      xfrag[t:256][k16:32][cg:4][p:2][lane:64][e:8]
//      hfrag[k16:64][cg:4][p:2][lane:64][e:8]
//   z0[tslot:32][s:128][lr:32][col:128] f32, lr = gate-row within slice.
// ---------------------------------------------------------------------------

// Prep 1: weights -> wfrag. Grid (96, 128) = (k16, s), 256 threads.
__global__ void prep_w(const float* __restrict__ Wgx, const float* __restrict__ Wix,
                       const float* __restrict__ Wfx, const float* __restrict__ Wox,
                       const float* __restrict__ Wgh, const float* __restrict__ Wih,
                       const float* __restrict__ Wfh, const float* __restrict__ Woh,
                       unsigned short* __restrict__ wfrag)
{
    const int k16 = blockIdx.x;        // 0..95
    const int s   = blockIdx.y;        // 0..127
    const int tid  = threadIdx.x;
    const int lane = tid >> 2;         // 0..63
    const int e0   = (tid & 3) * 2;    // 0,2,4,6
    const int row  = s * 32 + (lane & 31);
    const int k    = k16 * 16 + (lane >> 5) * 8 + e0;
    const int j = row >> 2;
    const int g = row & 3;
    float f0, f1;
    if (k < INP) {
        const float* wx = (g == 0 ? Wgx : g == 1 ? Wix : g == 2 ? Wfx : Wox) + (size_t)j * INP;
        f0 = wx[k]; f1 = wx[k + 1];
    } else {
        const float* wh = (g == 0 ? Wgh : g == 1 ? Wih : g == 2 ? Wfh : Woh) + (size_t)j * HID;
        f0 = wh[k - INP]; f1 = wh[k - INP + 1];
    }
    ushort2 hi, lo;
    hi.x = f2bf(f0); lo.x = f2bf(f0 - bf2f(hi.x));
    hi.y = f2bf(f1); lo.y = f2bf(f1 - bf2f(hi.y));
    unsigned short* base = wfrag + ((size_t)(s * NK16 + k16) * 2) * 512 + lane * 8 + e0;
    *(ushort2*)(base)       = hi;
    *(ushort2*)(base + 512) = lo;
}

// Prep 2: x -> xfrag. Grid (32, 256) = (k16x, t), 256 threads.
__global__ void prep_x(const float* __restrict__ x, unsigned short* __restrict__ xfrag)
{
    const int k16x = blockIdx.x;       // 0..31
    const int t    = blockIdx.y;       // 0..255
    const int tid  = threadIdx.x;
    const int cg   = tid >> 6;         // 0..3
    const int lane = tid & 63;
    const int col  = cg * 32 + (lane & 31);
    const int k0   = k16x * 16 + (lane >> 5) * 8;
    const float* src = x + ((size_t)col * TSTEPS + t) * INP + k0;
    const float4 v0 = *(const float4*)(src);
    const float4 v1 = *(const float4*)(src + 4);
    ushort4 h0, l0, h1, l1;
    h0.x = f2bf(v0.x); l0.x = f2bf(v0.x - bf2f(h0.x));
    h0.y = f2bf(v0.y); l0.y = f2bf(v0.y - bf2f(h0.y));
    h0.z = f2bf(v0.z); l0.z = f2bf(v0.z - bf2f(h0.z));
    h0.w = f2bf(v0.w); l0.w = f2bf(v0.w - bf2f(h0.w));
    h1.x = f2bf(v1.x); l1.x = f2bf(v1.x - bf2f(h1.x));
    h1.y = f2bf(v1.y); l1.y = f2bf(v1.y - bf2f(h1.y));
    h1.z = f2bf(v1.z); l1.z = f2bf(v1.z - bf2f(h1.z));
    h1.w = f2bf(v1.w); l1.w = f2bf(v1.w - bf2f(h1.w));
    unsigned short* base = xfrag +
        ((size_t)(((size_t)t * 32 + k16x) * 4 + cg) * 2) * 512 + lane * 8;
    *(ushort4*)(base)           = h0;
    *(ushort4*)(base + 4)       = h1;
    *(ushort4*)(base + 512)     = l0;
    *(ushort4*)(base + 512 + 4) = l1;
}

// Prep 3: c copy; h0 (H,B) -> hfrag0. 512 blocks x 256.
__global__ void prep_state(const float* __restrict__ cin, const float* __restrict__ hin,
                           float* __restrict__ cdst, unsigned short* __restrict__ hfrag0)
{
    const int idx = blockIdx.x * 256 + threadIdx.x;   // 0..131071
    cdst[idx] = cin[idx];
    const int j = idx >> 7;
    const int b = idx & 127;
    float f = hin[idx];
    unsigned short hh = f2bf(f);
    unsigned short hl = f2bf(f - bf2f(hh));
    const int k16h = j >> 4;
    const int hlf  = (j >> 3) & 1;
    const int e    = j & 7;
    const int cg   = b >> 5;
    const int lane = 32 * hlf + (b & 31);
    unsigned short* base = hfrag0 +
        ((size_t)((k16h * 4 + cg) * 2) * 512) + lane * 8 + e;
    base[0]   = hh;
    base[512] = hl;
}

// ---------------------------------------------------------------------------
// z0 chunk GEMM: z0[t][.] = Wx . x_t + b for t in [tbase, tbase+32).
// Grid (s:128, tq:32) x 512 thr. Block: 32 gate-rows x 128 cols, K=512.
// Waves: cw = wv&1 (cg pair 2cw,2cw+1), kq = wv>>1 (k16 = 4m+kq, m=0..7).
// Split-bf16 triple product, 2 chains/col-tile. Partials via 2-stage LDS.
// ---------------------------------------------------------------------------
__global__ __launch_bounds__(512, 2) void gemm_z0(
    const unsigned short* __restrict__ wfrag,
    const unsigned short* __restrict__ xfrag,
    float* __restrict__ z0,
    const float* __restrict__ bg, const float* __restrict__ bi,
    const float* __restrict__ bf_, const float* __restrict__ bo,
    int tbase)
{
    const int tid  = threadIdx.x;
    const int wv   = tid >> 6;
    const int lane = tid & 63;
    const int l31  = lane & 31;
    const int hl   = lane >> 5;
    const int cw   = wv & 1;
    const int kq   = wv >> 1;              // 0..3
    const int s    = blockIdx.x;           // 0..127
    const int t    = tbase + blockIdx.y;   // timestep
    const int tslot = t & (ZSLOTS - 1);

    // A: k16 = 4m + kq
    const unsigned short* pA = wfrag + ((size_t)(s * NK16 + kq) * 2) * 512 + lane * 8;
    // B: xfrag[t][k16][cg][p][512]; tiles cg = 2cw, 2cw+1
    const unsigned short* pB = xfrag + (size_t)t * 131072
                             + (size_t)(4 * kq + 2 * cw) * 1024 + lane * 8;

    f32x16 a0A, a0B, a1A, a1B;   // tile0/tile1, chains A=(Ah+Al)*Bh, B=Ah*Bl
#pragma unroll
    for (int r = 0; r < 16; ++r) { a0A[r]=0.f; a0B[r]=0.f; a1A[r]=0.f; a1B[r]=0.f; }

#pragma unroll
    for (int m = 0; m < 8; ++m) {
        short8 Ah  = LD8(pA);
        short8 Al  = LD8(pA + 512);
        short8 B0h = LD8(pB);
        short8 B0l = LD8(pB + 512);
        short8 B1h = LD8(pB + 1024);
        short8 B1l = LD8(pB + 1536);
        pA += 4096; pB += 16384;
        a0A = MFMA32(Ah, B0h, a0A);
        a1A = MFMA32(Ah, B1h, a1A);
        a0B = MFMA32(Ah, B0l, a0B);
        a1B = MFMA32(Ah, B1l, a1B);
        a0A = MFMA32(Al, B0h, a0A);
        a1A = MFMA32(Al, B1h, a1A);
    }

    __shared__ float part[2][32][128];     // 32 KB

    // stage 1: kq 2,3 dump; stage 2: kq 0,1 add.
    if (kq >= 2) {
#pragma unroll
        for (int r = 0; r < 16; ++r) {
            const int lr = (r & 3) + 8 * (r >> 2) + 4 * hl;
            part[kq - 2][lr][(2 * cw)     * 32 + l31] = a0A[r] + a0B[r];
            part[kq - 2][lr][(2 * cw + 1) * 32 + l31] = a1A[r] + a1B[r];
        }
    }
    __syncthreads();
    if (kq < 2) {
#pragma unroll
        for (int r = 0; r < 16; ++r) {
            const int lr = (r & 3) + 8 * (r >> 2) + 4 * hl;
            part[kq][lr][(2 * cw)     * 32 + l31] += a0A[r] + a0B[r];
            part[kq][lr][(2 * cw + 1) * 32 + l31] += a1A[r] + a1B[r];
        }
    }
    __syncthreads();

    // final: thread (lr = tid>>4, c0 = (tid&15)*8): z = p0+p1 + bias -> z0
    {
        const int lr = tid >> 4;
        const int c0 = (tid & 15) * 8;
        const int g  = lr & 3;
        const int j  = s * 8 + (lr >> 2);
        const float bb = (g == 0 ? bg : g == 1 ? bi : g == 2 ? bf_ : bo)[j];
        float z[8];
#pragma unroll
        for (int cc = 0; cc < 8; ++cc)
            z[cc] = part[0][lr][c0 + cc] + part[1][lr][c0 + cc] + bb;
        float* dst = z0 + (((size_t)tslot * 128 + s) * 32 + lr) * 128 + c0;
        *(float4*)(dst)     = make_float4(z[0], z[1], z[2], z[3]);
        *(float4*)(dst + 4) = make_float4(z[4], z[5], z[6], z[7]);
    }
}

// ---------------------------------------------------------------------------
// One LSTM timestep. Grid 256 x 512 (8 waves), 1 block/CU.
// XCD swizzle: xcd = bx&7 owns rowslices xcd*16..+15 (weight slice stays
// XCD-L2-resident across launches). Block: 32 gate-rows (8 j) x 64 cols.
// Waves = 8 pure K-slices (k16 = 8m + wv) covering BOTH 32-col tiles:
// no W or B duplication within the block.
// Mode A (z0 != null): K = h only (1024); gate pre-acts = partials + z0.
// Mode B (z0 == null): K = 1536 (x in-loop); pre-acts = partials + bias.
// ---------------------------------------------------------------------------
__global__ __launch_bounds__(512, 2) void lstm_step(
    const unsigned short* __restrict__ wfrag,
    const unsigned short* __restrict__ xfrag,
    const float* __restrict__ z0,
    const unsigned short* __restrict__ hin,
    unsigned short* __restrict__ hout,
    float* __restrict__ cst,
    const float* __restrict__ bg, const float* __restrict__ bi,
    const float* __restrict__ bf_, const float* __restrict__ bo,
    float* __restrict__ outf, int t)
{
    const int tid  = threadIdx.x;
    const int wv   = tid >> 6;             // K-slice 0..7
    const int lane = tid & 63;
    const int l31  = lane & 31;
    const int hl   = lane >> 5;
    const int bx   = blockIdx.x;

    const int xcd     = bx & 7;
    const int ii      = bx >> 3;
    const int s       = xcd * 16 + (ii >> 1);   // rowslice 0..127
    const int cb      = ii & 1;                 // col half
    const int colbase = cb << 6;
    const int J0      = s * 8;

    // epilogue role: thread = (jloc = tid>>6, cl = tid&63)
    const int ejl  = tid >> 6;
    const int ecl  = tid & 63;
    const int ej   = J0 + ejl;
    const int ecol = colbase + ecl;

    // preload additive terms + c (hides latency under K-loop)
    float add0, add1, add2, add3;
    if (z0) {
        const float* zp = z0 + (((size_t)(t & (ZSLOTS - 1)) * 128 + s) * 32
                                + 4 * ejl) * 128 + ecol;
        add0 = zp[0]; add1 = zp[128]; add2 = zp[256]; add3 = zp[384];
    } else {
        add0 = bg[ej]; add1 = bi[ej]; add2 = bf_[ej]; add3 = bo[ej];
    }
    const size_t ci = (size_t)ej * BATCH + ecol;
    float cold = cst[ci];

    f32x16 a0A, a0B, a1A, a1B;   // tile0/tile1 (cols 0-31 / 32-63 of block)
#pragma unroll
    for (int r = 0; r < 16; ++r) { a0A[r]=0.f; a0B[r]=0.f; a1A[r]=0.f; a1B[r]=0.f; }

    // B tile base offsets in act fragments: cg = 2*cb + tile
    const size_t bOff = (size_t)(4 * wv + 2 * cb) * 1024 + lane * 8;

    if (z0) {
        // h-only: k16h = 8m + wv, m = 0..7
        const unsigned short* pA = wfrag + ((size_t)(s * NK16 + 32 + wv) * 2) * 512 + lane * 8;
        const unsigned short* pH = hin + bOff;
#pragma unroll
        for (int m = 0; m < 8; ++m) {
            short8 Ah  = LD8(pA);
            short8 Al  = LD8(pA + 512);
            short8 B0h = LD8(pH);
            short8 B0l = LD8(pH + 512);
            short8 B1h = LD8(pH + 1024);
            short8 B1l = LD8(pH + 1536);
            pA += 8192; pH += 32768;
            a0A = MFMA32(Ah, B0h, a0A);
            a1A = MFMA32(Ah, B1h, a1A);
            a0B = MFMA32(Ah, B0l, a0B);
            a1B = MFMA32(Ah, B1l, a1B);
            a0A = MFMA32(Al, B0h, a0A);
            a1A = MFMA32(Al, B1h, a1A);
        }
    } else {
        // full K: k16 = 8m + wv, m=0..3 x-part, m=4..11 h-part
        const unsigned short* pA = wfrag + ((size_t)(s * NK16 + wv) * 2) * 512 + lane * 8;
        const unsigned short* pX = xfrag + (size_t)t * 131072 + bOff;
#pragma unroll
        for (int m = 0; m < 4; ++m) {
            short8 Ah  = LD8(pA);
            short8 Al  = LD8(pA + 512);
            short8 B0h = LD8(pX);
            short8 B0l = LD8(pX + 512);
            short8 B1h = LD8(pX + 1024);
            short8 B1l = LD8(pX + 1536);
            pA += 8192; pX += 32768;
            a0A = MFMA32(Ah, B0h, a0A);
            a1A = MFMA32(Ah, B1h, a1A);
            a0B = MFMA32(Ah, B0l, a0B);
            a1B = MFMA32(Ah, B1l, a1B);
            a0A = MFMA32(Al, B0h, a0A);
            a1A = MFMA32(Al, B1h, a1A);
        }
        const unsigned short* pH = hin + bOff;
#pragma unroll
        for (int m = 0; m < 8; ++m) {
            short8 Ah  = LD8(pA);
            short8 Al  = LD8(pA + 512);
            short8 B0h = LD8(pH);
            short8 B0l = LD8(pH + 512);
            short8 B1h = LD8(pH + 1024);
            short8 B1l = LD8(pH + 1536);
            pA += 8192; pH += 32768;
            a0A = MFMA32(Ah, B0h, a0A);
            a1A = MFMA32(Ah, B1h, a1A);
            a0B = MFMA32(Ah, B0l, a0B);
            a1B = MFMA32(Ah, B1l, a1B);
            a0A = MFMA32(Al, B0h, a0A);
            a1A = MFMA32(Al, B1h, a1A);
        }
    }

    __shared__ float part[4][32][64];          // 32 KB
    __shared__ unsigned short hti[8][64];
    __shared__ unsigned short htl[8][64];

    // two-stage K-partial reduction: waves 4..7 dump, 0..3 add-into.
    if (wv >= 4) {
#pragma unroll
        for (int r = 0; r < 16; ++r) {
            const int lr = (r & 3) + 8 * (r >> 2) + 4 * hl;
            part[wv - 4][lr][l31]      = a0A[r] + a0B[r];
            part[wv - 4][lr][32 + l31] = a1A[r] + a1B[r];
        }
    }
    __syncthreads();
    if (wv < 4) {
#pragma unroll
        for (int r = 0; r < 16; ++r) {
            const int lr = (r & 3) + 8 * (r >> 2) + 4 * hl;
            part[wv][lr][l31]      += a0A[r] + a0B[r];
            part[wv][lr][32 + l31] += a1A[r] + a1B[r];
        }
    }
    __syncthreads();

    // gates: thread (ejl, ecl)
    {
        const int r0 = 4 * ejl;
        float z0g = part[0][r0+0][ecl] + part[1][r0+0][ecl] + part[2][r0+0][ecl] + part[3][r0+0][ecl] + add0;
        float z1g = part[0][r0+1][ecl] + part[1][r0+1][ecl] + part[2][r0+1][ecl] + part[3][r0+1][ecl] + add1;
        float z2g = part[0][r0+2][ecl] + part[1][r0+2][ecl] + part[2][r0+2][ecl] + part[3][r0+2][ecl] + add2;
        float z3g = part[0][r0+3][ecl] + part[1][r0+3][ecl] + part[2][r0+3][ecl] + part[3][r0+3][ecl] + add3;
        float gg = tanh_f(z0g);
        float ig = sigmoid_f(z1g);
        float fg = sigmoid_f(z2g);
        float og = sigmoid_f(z3g);
        float cn = gg * ig + cold * fg;
        cst[ci] = cn;
        float hh = tanh_f(cn) * og;
        unsigned short hb = f2bf(hh);
        hti[ejl][ecl] = hb;
        htl[ejl][ecl] = f2bf(hh - bf2f(hb));
        if (outf) outf[ci] = hh;
    }
    __syncthreads();

    // h write-back in fragment-major layout (round-4 verified writer).
    if (tid < 256) {
        const int cgl  = tid >> 7;            // local col-group 0/1
        const int p    = (tid >> 6) & 1;      // hi/lo
        const int c5   = (tid >> 1) & 31;     // col within group
        const int q4   = (tid & 1) * 4;       // e quad
        const int coll = cgl * 32 + c5;
        unsigned short (*src)[64] = p ? htl : hti;
        ushort4 v;
        v.x = src[q4 + 0][coll]; v.y = src[q4 + 1][coll];
        v.z = src[q4 + 2][coll]; v.w = src[q4 + 3][coll];
        const int k16h = s >> 1;
        const int lh   = 32 * (s & 1) + c5;
        const int cgg  = (colbase >> 5) + cgl;
        unsigned short* dst = hout +
            ((size_t)((k16h * 4 + cgg) * 2 + p) * 512) + lh * 8 + q4;
        *(ushort4*)dst = v;
    }
}

// ---------------------------------------------------------------------------
extern "C" void kernel_launch(void* const* d_in, const int* in_sizes, int n_in,
                              void* d_out, int out_size, void* d_ws, size_t ws_size,
                              hipStream_t stream)
{
    const float* x   = (const float*)d_in[0];
    const float* c0v = (const float*)d_in[1];
    const float* h0v = (const float*)d_in[2];
    const float* Wgx = (const float*)d_in[3];
    const float* Wix = (const float*)d_in[4];
    const float* Wfx = (const float*)d_in[5];
    const float* Wox = (const float*)d_in[6];
    const float* Wgh = (const float*)d_in[7];
    const float* Wih = (const float*)d_in[8];
    const float* Wfh = (const float*)d_in[9];
    const float* Woh = (const float*)d_in[10];
    const float* bg  = (const float*)d_in[11];
    const float* bi  = (const float*)d_in[12];
    const float* bf  = (const float*)d_in[13];
    const float* bo  = (const float*)d_in[14];

    // ws layout (ushort unless noted):
    //   wfrag 25.2 MB | xfrag 67.1 MB | hf0,hf1 0.5 MB ea | cst 0.5 MB
    //   z0 64 MB (f32, only if ws_size permits)  => mode-A total ~161 MB
    unsigned short* wfrag = (unsigned short*)d_ws;
    unsigned short* xfrag = wfrag + (size_t)128 * NK16 * 2 * 512;
    unsigned short* hf0   = xfrag + (size_t)TSTEPS * 32 * 4 * 2 * 512;
    unsigned short* hf1   = hf0 + (size_t)64 * 4 * 2 * 512;
    float* cst            = (float*)(hf1 + (size_t)64 * 4 * 2 * 512);
    float* z0             = (float*)(cst + (size_t)HID * BATCH);

    const size_t needA = (size_t)((char*)(z0 + (size_t)ZSLOTS * 4096 * 128) - (char*)d_ws);
    const bool useA = (ws_size >= needA);

    unsigned short* hf[2] = { hf0, hf1 };
    float* outp = (float*)d_out;

    prep_w<<<dim3(NK16, 128), dim3(256), 0, stream>>>(Wgx, Wix, Wfx, Wox,
                                                      Wgh, Wih, Wfh, Woh, wfrag);
    prep_x<<<dim3(32, TSTEPS), dim3(256), 0, stream>>>(x, xfrag);
    prep_state<<<dim3(512), dim3(256), 0, stream>>>(c0v, h0v, cst, hf[0]);

    if (useA) {
        for (int q = 0; q < TSTEPS / ZSLOTS; ++q) {
            gemm_z0<<<dim3(128, ZSLOTS), dim3(512), 0, stream>>>(
                wfrag, xfrag, z0, bg, bi, bf, bo, q * ZSLOTS);
            for (int tt = 0; tt < ZSLOTS; ++tt) {
                const int t = q * ZSLOTS + tt;
                lstm_step<<<dim3(256), dim3(512), 0, stream>>>(
                    wfrag, xfrag, z0, hf[t & 1], hf[(t + 1) & 1],
                    cst, bg, bi, bf, bo,
                    (t == TSTEPS - 1) ? outp : nullptr, t);
            }
        }
    } else {
        for (int t = 0; t < TSTEPS; ++t) {
            lstm_step<<<dim3(256), dim3(512), 0, stream>>>(
                wfrag, xfrag, nullptr, hf[t & 1], hf[(t + 1) & 1],
                cst, bg, bi, bf, bo,
                (t == TSTEPS - 1) ? outp : nullptr, t);
        }
    }
}

// Round 7
// 2756.555 us; speedup vs baseline: 4.8101x; 1.0022x over previous
//
#include <hip/hip_runtime.h>
#include <cstdint>
#include <cstddef>

#define HID 1024
#define INP 512
#define BATCH 128
#define TSTEPS 256
#define NK16 96         // K/16 total (x: 0..31, h: 32..95)
#define ZSLOTS 32       // rotating z0 chunk depth (t mod 32)

using short8  = __attribute__((ext_vector_type(8))) short;
using f32x16  = __attribute__((ext_vector_type(16))) float;

#define LD8(p) (*(const short8*)(p))
#define MFMA32(a,b,c) __builtin_amdgcn_mfma_f32_32x32x16_bf16((a),(b),(c),0,0,0)

static __device__ __forceinline__ unsigned short f2bf(float f) {
    union { float f; unsigned int u; } v; v.f = f;
    unsigned int r = v.u + 0x7fffu + ((v.u >> 16) & 1u);   // RNE
    return (unsigned short)(r >> 16);
}
static __device__ __forceinline__ float bf2f(unsigned short b) {
    union { unsigned int u; float f; } v; v.u = ((unsigned int)b) << 16;
    return v.f;
}
static __device__ __forceinline__ float sigmoid_f(float z) {
    return 1.0f / (1.0f + __expf(-z));
}
static __device__ __forceinline__ float tanh_f(float z) {
    return 2.0f / (1.0f + __expf(-2.0f * z)) - 1.0f;
}

// ---------------------------------------------------------------------------
// Fragment layouts (32x32x16 MFMA; verified rounds 4-6):
//   A: lane l holds W[s*32 + (l&31)][k16*16 + (l>>5)*8 + e]
//      wfrag[s:128][k16:96][p:2][lane:64][e:8]   (p: 0=hi, 1=lo)
//   B: lane l holds act[col = cg*32 + (l&31)][k16*16 + (l>>5)*8 + e]
//      xfrag[t:256][k16:32][cg:4][p:2][lane:64][e:8]
//      hfrag[k16:64][cg:4][p:2][lane:64][e:8]
//   z0[tslot:32][s:128][lr:32][col:128] f32, lr = gate-row within slice.
// ---------------------------------------------------------------------------

// Prep 1: weights -> wfrag. Grid (96, 128) = (k16, s), 256 threads.
__global__ void prep_w(const float* __restrict__ Wgx, const float* __restrict__ Wix,
                       const float* __restrict__ Wfx, const float* __restrict__ Wox,
                       const float* __restrict__ Wgh, const float* __restrict__ Wih,
                       const float* __restrict__ Wfh, const float* __restrict__ Woh,
                       unsigned short* __restrict__ wfrag)
{
    const int k16 = blockIdx.x;        // 0..95
    const int s   = blockIdx.y;        // 0..127
    const int tid  = threadIdx.x;
    const int lane = tid >> 2;         // 0..63
    const int e0   = (tid & 3) * 2;    // 0,2,4,6
    const int row  = s * 32 + (lane & 31);
    const int k    = k16 * 16 + (lane >> 5) * 8 + e0;
    const int j = row >> 2;
    const int g = row & 3;
    float f0, f1;
    if (k < INP) {
        const float* wx = (g == 0 ? Wgx : g == 1 ? Wix : g == 2 ? Wfx : Wox) + (size_t)j * INP;
        f0 = wx[k]; f1 = wx[k + 1];
    } else {
        const float* wh = (g == 0 ? Wgh : g == 1 ? Wih : g == 2 ? Wfh : Woh) + (size_t)j * HID;
        f0 = wh[k - INP]; f1 = wh[k - INP + 1];
    }
    ushort2 hi, lo;
    hi.x = f2bf(f0); lo.x = f2bf(f0 - bf2f(hi.x));
    hi.y = f2bf(f1); lo.y = f2bf(f1 - bf2f(hi.y));
    unsigned short* base = wfrag + ((size_t)(s * NK16 + k16) * 2) * 512 + lane * 8 + e0;
    *(ushort2*)(base)       = hi;
    *(ushort2*)(base + 512) = lo;
}

// Prep 2: x -> xfrag. Grid (32, 256) = (k16x, t), 256 threads.
__global__ void prep_x(const float* __restrict__ x, unsigned short* __restrict__ xfrag)
{
    const int k16x = blockIdx.x;       // 0..31
    const int t    = blockIdx.y;       // 0..255
    const int tid  = threadIdx.x;
    const int cg   = tid >> 6;         // 0..3
    const int lane = tid & 63;
    const int col  = cg * 32 + (lane & 31);
    const int k0   = k16x * 16 + (lane >> 5) * 8;
    const float* src = x + ((size_t)col * TSTEPS + t) * INP + k0;
    const float4 v0 = *(const float4*)(src);
    const float4 v1 = *(const float4*)(src + 4);
    ushort4 h0, l0, h1, l1;
    h0.x = f2bf(v0.x); l0.x = f2bf(v0.x - bf2f(h0.x));
    h0.y = f2bf(v0.y); l0.y = f2bf(v0.y - bf2f(h0.y));
    h0.z = f2bf(v0.z); l0.z = f2bf(v0.z - bf2f(h0.z));
    h0.w = f2bf(v0.w); l0.w = f2bf(v0.w - bf2f(h0.w));
    h1.x = f2bf(v1.x); l1.x = f2bf(v1.x - bf2f(h1.x));
    h1.y = f2bf(v1.y); l1.y = f2bf(v1.y - bf2f(h1.y));
    h1.z = f2bf(v1.z); l1.z = f2bf(v1.z - bf2f(h1.z));
    h1.w = f2bf(v1.w); l1.w = f2bf(v1.w - bf2f(h1.w));
    unsigned short* base = xfrag +
        ((size_t)(((size_t)t * 32 + k16x) * 4 + cg) * 2) * 512 + lane * 8;
    *(ushort4*)(base)           = h0;
    *(ushort4*)(base + 4)       = h1;
    *(ushort4*)(base + 512)     = l0;
    *(ushort4*)(base + 512 + 4) = l1;
}

// Prep 3: c copy; h0 (H,B) -> hfrag0. 512 blocks x 256.
__global__ void prep_state(const float* __restrict__ cin, const float* __restrict__ hin,
                           float* __restrict__ cdst, unsigned short* __restrict__ hfrag0)
{
    const int idx = blockIdx.x * 256 + threadIdx.x;   // 0..131071
    cdst[idx] = cin[idx];
    const int j = idx >> 7;
    const int b = idx & 127;
    float f = hin[idx];
    unsigned short hh = f2bf(f);
    unsigned short hl = f2bf(f - bf2f(hh));
    const int k16h = j >> 4;
    const int hlf  = (j >> 3) & 1;
    const int e    = j & 7;
    const int cg   = b >> 5;
    const int lane = 32 * hlf + (b & 31);
    unsigned short* base = hfrag0 +
        ((size_t)((k16h * 4 + cg) * 2) * 512) + lane * 8 + e;
    base[0]   = hh;
    base[512] = hl;
}

// ---------------------------------------------------------------------------
// z0 chunk GEMM: z0[t][.] = Wx . x_t + b for t in [tbase, tbase+32).
// Grid (s:128, tq:32) x 512 thr. Block: 32 gate-rows x 128 cols, K=512.
// Waves: cw = wv&1 (cg pair 2cw,2cw+1), kq = wv>>1 (k16 = 4m+kq, m=0..7).
// Split-bf16 triple product, 2 chains/col-tile. Partials via 2-stage LDS.
// launch_bounds (512,2): grid is 16 blocks/CU deep, co-residency > VGPRs here.
// ---------------------------------------------------------------------------
__global__ __launch_bounds__(512, 2) void gemm_z0(
    const unsigned short* __restrict__ wfrag,
    const unsigned short* __restrict__ xfrag,
    float* __restrict__ z0,
    const float* __restrict__ bg, const float* __restrict__ bi,
    const float* __restrict__ bf_, const float* __restrict__ bo,
    int tbase)
{
    const int tid  = threadIdx.x;
    const int wv   = tid >> 6;
    const int lane = tid & 63;
    const int l31  = lane & 31;
    const int hl   = lane >> 5;
    const int cw   = wv & 1;
    const int kq   = wv >> 1;              // 0..3
    const int s    = blockIdx.x;           // 0..127
    const int t    = tbase + blockIdx.y;   // timestep
    const int tslot = t & (ZSLOTS - 1);

    // A: k16 = 4m + kq
    const unsigned short* pA = wfrag + ((size_t)(s * NK16 + kq) * 2) * 512 + lane * 8;
    // B: xfrag[t][k16][cg][p][512]; tiles cg = 2cw, 2cw+1
    const unsigned short* pB = xfrag + (size_t)t * 131072
                             + (size_t)(4 * kq + 2 * cw) * 1024 + lane * 8;

    f32x16 a0A, a0B, a1A, a1B;   // tile0/tile1, chains A=(Ah+Al)*Bh, B=Ah*Bl
#pragma unroll
    for (int r = 0; r < 16; ++r) { a0A[r]=0.f; a0B[r]=0.f; a1A[r]=0.f; a1B[r]=0.f; }

#pragma unroll
    for (int m = 0; m < 8; ++m) {
        short8 Ah  = LD8(pA);
        short8 Al  = LD8(pA + 512);
        short8 B0h = LD8(pB);
        short8 B0l = LD8(pB + 512);
        short8 B1h = LD8(pB + 1024);
        short8 B1l = LD8(pB + 1536);
        pA += 4096; pB += 16384;
        a0A = MFMA32(Ah, B0h, a0A);
        a1A = MFMA32(Ah, B1h, a1A);
        a0B = MFMA32(Ah, B0l, a0B);
        a1B = MFMA32(Ah, B1l, a1B);
        a0A = MFMA32(Al, B0h, a0A);
        a1A = MFMA32(Al, B1h, a1A);
    }

    __shared__ float part[2][32][128];     // 32 KB

    // stage 1: kq 2,3 dump; stage 2: kq 0,1 add.
    if (kq >= 2) {
#pragma unroll
        for (int r = 0; r < 16; ++r) {
            const int lr = (r & 3) + 8 * (r >> 2) + 4 * hl;
            part[kq - 2][lr][(2 * cw)     * 32 + l31] = a0A[r] + a0B[r];
            part[kq - 2][lr][(2 * cw + 1) * 32 + l31] = a1A[r] + a1B[r];
        }
    }
    __syncthreads();
    if (kq < 2) {
#pragma unroll
        for (int r = 0; r < 16; ++r) {
            const int lr = (r & 3) + 8 * (r >> 2) + 4 * hl;
            part[kq][lr][(2 * cw)     * 32 + l31] += a0A[r] + a0B[r];
            part[kq][lr][(2 * cw + 1) * 32 + l31] += a1A[r] + a1B[r];
        }
    }
    __syncthreads();

    // final: thread (lr = tid>>4, c0 = (tid&15)*8): z = p0+p1 + bias -> z0
    {
        const int lr = tid >> 4;
        const int c0 = (tid & 15) * 8;
        const int g  = lr & 3;
        const int j  = s * 8 + (lr >> 2);
        const float bb = (g == 0 ? bg : g == 1 ? bi : g == 2 ? bf_ : bo)[j];
        float z[8];
#pragma unroll
        for (int cc = 0; cc < 8; ++cc)
            z[cc] = part[0][lr][c0 + cc] + part[1][lr][c0 + cc] + bb;
        float* dst = z0 + (((size_t)tslot * 128 + s) * 32 + lr) * 128 + c0;
        *(float4*)(dst)     = make_float4(z[0], z[1], z[2], z[3]);
        *(float4*)(dst + 4) = make_float4(z[4], z[5], z[6], z[7]);
    }
}

// ---------------------------------------------------------------------------
// One LSTM timestep. Grid 256 x 512 (8 waves), 1 block/CU.
// XCD swizzle: xcd = bx&7 owns rowslices xcd*16..+15 (weight slice stays
// XCD-L2-resident across launches). Block: 32 gate-rows (8 j) x 64 cols.
// Waves = 8 pure K-slices (k16 = 8m + wv) covering BOTH 32-col tiles:
// no W or B duplication within the block.
// Mode A (z0 != null): K = h only (1024); gate pre-acts = partials + z0.
// Mode B (z0 == null): K = 1536 (x in-loop); pre-acts = partials + bias.
// launch_bounds (512,1): grid is exactly 1 block/CU, so extra-wave occupancy
// is unusable; give the allocator the full 256-VGPR budget instead so the
// fully-unrolled K-loop can keep ~2-3x more global loads in flight.
// (Block residency itself caps V at 256: 8 waves x 256 = 2048 = CU pool.)
// ---------------------------------------------------------------------------
__global__ __launch_bounds__(512, 1) void lstm_step(
    const unsigned short* __restrict__ wfrag,
    const unsigned short* __restrict__ xfrag,
    const float* __restrict__ z0,
    const unsigned short* __restrict__ hin,
    unsigned short* __restrict__ hout,
    float* __restrict__ cst,
    const float* __restrict__ bg, const float* __restrict__ bi,
    const float* __restrict__ bf_, const float* __restrict__ bo,
    float* __restrict__ outf, int t)
{
    const int tid  = threadIdx.x;
    const int wv   = tid >> 6;             // K-slice 0..7
    const int lane = tid & 63;
    const int l31  = lane & 31;
    const int hl   = lane >> 5;
    const int bx   = blockIdx.x;

    const int xcd     = bx & 7;
    const int ii      = bx >> 3;
    const int s       = xcd * 16 + (ii >> 1);   // rowslice 0..127
    const int cb      = ii & 1;                 // col half
    const int colbase = cb << 6;
    const int J0      = s * 8;

    // epilogue role: thread = (jloc = tid>>6, cl = tid&63)
    const int ejl  = tid >> 6;
    const int ecl  = tid & 63;
    const int ej   = J0 + ejl;
    const int ecol = colbase + ecl;

    // preload additive terms + c (hides latency under K-loop)
    float add0, add1, add2, add3;
    if (z0) {
        const float* zp = z0 + (((size_t)(t & (ZSLOTS - 1)) * 128 + s) * 32
                                + 4 * ejl) * 128 + ecol;
        add0 = zp[0]; add1 = zp[128]; add2 = zp[256]; add3 = zp[384];
    } else {
        add0 = bg[ej]; add1 = bi[ej]; add2 = bf_[ej]; add3 = bo[ej];
    }
    const size_t ci = (size_t)ej * BATCH + ecol;
    float cold = cst[ci];

    f32x16 a0A, a0B, a1A, a1B;   // tile0/tile1 (cols 0-31 / 32-63 of block)
#pragma unroll
    for (int r = 0; r < 16; ++r) { a0A[r]=0.f; a0B[r]=0.f; a1A[r]=0.f; a1B[r]=0.f; }

    // B tile base offsets in act fragments: cg = 2*cb + tile
    const size_t bOff = (size_t)(4 * wv + 2 * cb) * 1024 + lane * 8;

    if (z0) {
        // h-only: k16h = 8m + wv, m = 0..7
        const unsigned short* pA = wfrag + ((size_t)(s * NK16 + 32 + wv) * 2) * 512 + lane * 8;
        const unsigned short* pH = hin + bOff;
#pragma unroll
        for (int m = 0; m < 8; ++m) {
            short8 Ah  = LD8(pA);
            short8 Al  = LD8(pA + 512);
            short8 B0h = LD8(pH);
            short8 B0l = LD8(pH + 512);
            short8 B1h = LD8(pH + 1024);
            short8 B1l = LD8(pH + 1536);
            pA += 8192; pH += 32768;
            a0A = MFMA32(Ah, B0h, a0A);
            a1A = MFMA32(Ah, B1h, a1A);
            a0B = MFMA32(Ah, B0l, a0B);
            a1B = MFMA32(Ah, B1l, a1B);
            a0A = MFMA32(Al, B0h, a0A);
            a1A = MFMA32(Al, B1h, a1A);
        }
    } else {
        // full K: k16 = 8m + wv, m=0..3 x-part, m=4..11 h-part
        const unsigned short* pA = wfrag + ((size_t)(s * NK16 + wv) * 2) * 512 + lane * 8;
        const unsigned short* pX = xfrag + (size_t)t * 131072 + bOff;
#pragma unroll
        for (int m = 0; m < 4; ++m) {
            short8 Ah  = LD8(pA);
            short8 Al  = LD8(pA + 512);
            short8 B0h = LD8(pX);
            short8 B0l = LD8(pX + 512);
            short8 B1h = LD8(pX + 1024);
            short8 B1l = LD8(pX + 1536);
            pA += 8192; pX += 32768;
            a0A = MFMA32(Ah, B0h, a0A);
            a1A = MFMA32(Ah, B1h, a1A);
            a0B = MFMA32(Ah, B0l, a0B);
            a1B = MFMA32(Ah, B1l, a1B);
            a0A = MFMA32(Al, B0h, a0A);
            a1A = MFMA32(Al, B1h, a1A);
        }
        const unsigned short* pH = hin + bOff;
#pragma unroll
        for (int m = 0; m < 8; ++m) {
            short8 Ah  = LD8(pA);
            short8 Al  = LD8(pA + 512);
            short8 B0h = LD8(pH);
            short8 B0l = LD8(pH + 512);
            short8 B1h = LD8(pH + 1024);
            short8 B1l = LD8(pH + 1536);
            pA += 8192; pH += 32768;
            a0A = MFMA32(Ah, B0h, a0A);
            a1A = MFMA32(Ah, B1h, a1A);
            a0B = MFMA32(Ah, B0l, a0B);
            a1B = MFMA32(Ah, B1l, a1B);
            a0A = MFMA32(Al, B0h, a0A);
            a1A = MFMA32(Al, B1h, a1A);
        }
    }

    __shared__ float part[4][32][64];          // 32 KB
    __shared__ unsigned short hti[8][64];
    __shared__ unsigned short htl[8][64];

    // two-stage K-partial reduction: waves 4..7 dump, 0..3 add-into.
    if (wv >= 4) {
#pragma unroll
        for (int r = 0; r < 16; ++r) {
            const int lr = (r & 3) + 8 * (r >> 2) + 4 * hl;
            part[wv - 4][lr][l31]      = a0A[r] + a0B[r];
            part[wv - 4][lr][32 + l31] = a1A[r] + a1B[r];
        }
    }
    __syncthreads();
    if (wv < 4) {
#pragma unroll
        for (int r = 0; r < 16; ++r) {
            const int lr = (r & 3) + 8 * (r >> 2) + 4 * hl;
            part[wv][lr][l31]      += a0A[r] + a0B[r];
            part[wv][lr][32 + l31] += a1A[r] + a1B[r];
        }
    }
    __syncthreads();

    // gates: thread (ejl, ecl)
    {
        const int r0 = 4 * ejl;
        float z0g = part[0][r0+0][ecl] + part[1][r0+0][ecl] + part[2][r0+0][ecl] + part[3][r0+0][ecl] + add0;
        float z1g = part[0][r0+1][ecl] + part[1][r0+1][ecl] + part[2][r0+1][ecl] + part[3][r0+1][ecl] + add1;
        float z2g = part[0][r0+2][ecl] + part[1][r0+2][ecl] + part[2][r0+2][ecl] + part[3][r0+2][ecl] + add2;
        float z3g = part[0][r0+3][ecl] + part[1][r0+3][ecl] + part[2][r0+3][ecl] + part[3][r0+3][ecl] + add3;
        float gg = tanh_f(z0g);
        float ig = sigmoid_f(z1g);
        float fg = sigmoid_f(z2g);
        float og = sigmoid_f(z3g);
        float cn = gg * ig + cold * fg;
        cst[ci] = cn;
        float hh = tanh_f(cn) * og;
        unsigned short hb = f2bf(hh);
        hti[ejl][ecl] = hb;
        htl[ejl][ecl] = f2bf(hh - bf2f(hb));
        if (outf) outf[ci] = hh;
    }
    __syncthreads();

    // h write-back in fragment-major layout (round-4 verified writer).
    if (tid < 256) {
        const int cgl  = tid >> 7;            // local col-group 0/1
        const int p    = (tid >> 6) & 1;      // hi/lo
        const int c5   = (tid >> 1) & 31;     // col within group
        const int q4   = (tid & 1) * 4;       // e quad
        const int coll = cgl * 32 + c5;
        unsigned short (*src)[64] = p ? htl : hti;
        ushort4 v;
        v.x = src[q4 + 0][coll]; v.y = src[q4 + 1][coll];
        v.z = src[q4 + 2][coll]; v.w = src[q4 + 3][coll];
        const int k16h = s >> 1;
        const int lh   = 32 * (s & 1) + c5;
        const int cgg  = (colbase >> 5) + cgl;
        unsigned short* dst = hout +
            ((size_t)((k16h * 4 + cgg) * 2 + p) * 512) + lh * 8 + q4;
        *(ushort4*)dst = v;
    }
}

// ---------------------------------------------------------------------------
extern "C" void kernel_launch(void* const* d_in, const int* in_sizes, int n_in,
                              void* d_out, int out_size, void* d_ws, size_t ws_size,
                              hipStream_t stream)
{
    const float* x   = (const float*)d_in[0];
    const float* c0v = (const float*)d_in[1];
    const float* h0v = (const float*)d_in[2];
    const float* Wgx = (const float*)d_in[3];
    const float* Wix = (const float*)d_in[4];
    const float* Wfx = (const float*)d_in[5];
    const float* Wox = (const float*)d_in[6];
    const float* Wgh = (const float*)d_in[7];
    const float* Wih = (const float*)d_in[8];
    const float* Wfh = (const float*)d_in[9];
    const float* Woh = (const float*)d_in[10];
    const float* bg  = (const float*)d_in[11];
    const float* bi  = (const float*)d_in[12];
    const float* bf  = (const float*)d_in[13];
    const float* bo  = (const float*)d_in[14];

    // ws layout (ushort unless noted):
    //   wfrag 25.2 MB | xfrag 67.1 MB | hf0,hf1 0.5 MB ea | cst 0.5 MB
    //   z0 64 MB (f32, only if ws_size permits)  => mode-A total ~161 MB
    unsigned short* wfrag = (unsigned short*)d_ws;
    unsigned short* xfrag = wfrag + (size_t)128 * NK16 * 2 * 512;
    unsigned short* hf0   = xfrag + (size_t)TSTEPS * 32 * 4 * 2 * 512;
    unsigned short* hf1   = hf0 + (size_t)64 * 4 * 2 * 512;
    float* cst            = (float*)(hf1 + (size_t)64 * 4 * 2 * 512);
    float* z0             = (float*)(cst + (size_t)HID * BATCH);

    const size_t needA = (size_t)((char*)(z0 + (size_t)ZSLOTS * 4096 * 128) - (char*)d_ws);
    const bool useA = (ws_size >= needA);

    unsigned short* hf[2] = { hf0, hf1 };
    float* outp = (float*)d_out;

    prep_w<<<dim3(NK16, 128), dim3(256), 0, stream>>>(Wgx, Wix, Wfx, Wox,
                                                      Wgh, Wih, Wfh, Woh, wfrag);
    prep_x<<<dim3(32, TSTEPS), dim3(256), 0, stream>>>(x, xfrag);
    prep_state<<<dim3(512), dim3(256), 0, stream>>>(c0v, h0v, cst, hf[0]);

    if (useA) {
        for (int q = 0; q < TSTEPS / ZSLOTS; ++q) {
            gemm_z0<<<dim3(128, ZSLOTS), dim3(512), 0, stream>>>(
                wfrag, xfrag, z0, bg, bi, bf, bo, q * ZSLOTS);
            for (int tt = 0; tt < ZSLOTS; ++tt) {
                const int t = q * ZSLOTS + tt;
                lstm_step<<<dim3(256), dim3(512), 0, stream>>>(
                    wfrag, xfrag, z0, hf[t & 1], hf[(t + 1) & 1],
                    cst, bg, bi, bf, bo,
                    (t == TSTEPS - 1) ? outp : nullptr, t);
            }
        }
    } else {
        for (int t = 0; t < TSTEPS; ++t) {
            lstm_step<<<dim3(256), dim3(512), 0, stream>>>(
                wfrag, xfrag, nullptr, hf[t & 1], hf[(t + 1) & 1],
                cst, bg, bi, bf, bo,
                (t == TSTEPS - 1) ? outp : nullptr, t);
        }
    }
}

// Round 8
// 2518.206 us; speedup vs baseline: 5.2654x; 1.0947x over previous
//
#include <hip/hip_runtime.h>
#include <cstdint>
#include <cstddef>

#define HID 1024
#define INP 512
#define BATCH 128
#define TSTEPS 256
#define NK16 96         // K/16 total (x: 0..31, h: 32..95)
#define ZSLOTS 32       // rotating z0 chunk depth (t mod 32)

using short8  = __attribute__((ext_vector_type(8))) short;
using f32x16  = __attribute__((ext_vector_type(16))) float;

#define LD8(p) (*(const short8*)(p))
#define MFMA32(a,b,c) __builtin_amdgcn_mfma_f32_32x32x16_bf16((a),(b),(c),0,0,0)

static __device__ __forceinline__ unsigned short f2bf(float f) {
    union { float f; unsigned int u; } v; v.f = f;
    unsigned int r = v.u + 0x7fffu + ((v.u >> 16) & 1u);   // RNE
    return (unsigned short)(r >> 16);
}
static __device__ __forceinline__ float bf2f(unsigned short b) {
    union { unsigned int u; float f; } v; v.u = ((unsigned int)b) << 16;
    return v.f;
}
static __device__ __forceinline__ float sigmoid_f(float z) {
    return 1.0f / (1.0f + __expf(-z));
}
static __device__ __forceinline__ float tanh_f(float z) {
    return 2.0f / (1.0f + __expf(-2.0f * z)) - 1.0f;
}

// ---------------------------------------------------------------------------
// Fragment layouts (32x32x16 MFMA; verified rounds 4-7):
//   A: lane l holds W[s*32 + (l&31)][k16*16 + (l>>5)*8 + e]
//      wfrag[s:128][k16:96][p:2][lane:64][e:8]   (p: 0=hi, 1=lo)
//   B: lane l holds act[col = cg*32 + (l&31)][k16*16 + (l>>5)*8 + e]
//      xfrag[t:256][k16:32][cg:4][p:2][lane:64][e:8]
//      hfrag[k16:64][cg:4][p:2][lane:64][e:8]
//   z0[tslot:32][s:128][lr:32][col:128] f32, lr = gate-row within slice.
// ---------------------------------------------------------------------------

// Prep 1: weights -> wfrag. Grid (96, 128) = (k16, s), 256 threads.
__global__ void prep_w(const float* __restrict__ Wgx, const float* __restrict__ Wix,
                       const float* __restrict__ Wfx, const float* __restrict__ Wox,
                       const float* __restrict__ Wgh, const float* __restrict__ Wih,
                       const float* __restrict__ Wfh, const float* __restrict__ Woh,
                       unsigned short* __restrict__ wfrag)
{
    const int k16 = blockIdx.x;        // 0..95
    const int s   = blockIdx.y;        // 0..127
    const int tid  = threadIdx.x;
    const int lane = tid >> 2;         // 0..63
    const int e0   = (tid & 3) * 2;    // 0,2,4,6
    const int row  = s * 32 + (lane & 31);
    const int k    = k16 * 16 + (lane >> 5) * 8 + e0;
    const int j = row >> 2;
    const int g = row & 3;
    float f0, f1;
    if (k < INP) {
        const float* wx = (g == 0 ? Wgx : g == 1 ? Wix : g == 2 ? Wfx : Wox) + (size_t)j * INP;
        f0 = wx[k]; f1 = wx[k + 1];
    } else {
        const float* wh = (g == 0 ? Wgh : g == 1 ? Wih : g == 2 ? Wfh : Woh) + (size_t)j * HID;
        f0 = wh[k - INP]; f1 = wh[k - INP + 1];
    }
    ushort2 hi, lo;
    hi.x = f2bf(f0); lo.x = f2bf(f0 - bf2f(hi.x));
    hi.y = f2bf(f1); lo.y = f2bf(f1 - bf2f(hi.y));
    unsigned short* base = wfrag + ((size_t)(s * NK16 + k16) * 2) * 512 + lane * 8 + e0;
    *(ushort2*)(base)       = hi;
    *(ushort2*)(base + 512) = lo;
}

// Prep 2: x -> xfrag. Grid (32, 256) = (k16x, t), 256 threads.
__global__ void prep_x(const float* __restrict__ x, unsigned short* __restrict__ xfrag)
{
    const int k16x = blockIdx.x;       // 0..31
    const int t    = blockIdx.y;       // 0..255
    const int tid  = threadIdx.x;
    const int cg   = tid >> 6;         // 0..3
    const int lane = tid & 63;
    const int col  = cg * 32 + (lane & 31);
    const int k0   = k16x * 16 + (lane >> 5) * 8;
    const float* src = x + ((size_t)col * TSTEPS + t) * INP + k0;
    const float4 v0 = *(const float4*)(src);
    const float4 v1 = *(const float4*)(src + 4);
    ushort4 h0, l0, h1, l1;
    h0.x = f2bf(v0.x); l0.x = f2bf(v0.x - bf2f(h0.x));
    h0.y = f2bf(v0.y); l0.y = f2bf(v0.y - bf2f(h0.y));
    h0.z = f2bf(v0.z); l0.z = f2bf(v0.z - bf2f(h0.z));
    h0.w = f2bf(v0.w); l0.w = f2bf(v0.w - bf2f(h0.w));
    h1.x = f2bf(v1.x); l1.x = f2bf(v1.x - bf2f(h1.x));
    h1.y = f2bf(v1.y); l1.y = f2bf(v1.y - bf2f(h1.y));
    h1.z = f2bf(v1.z); l1.z = f2bf(v1.z - bf2f(h1.z));
    h1.w = f2bf(v1.w); l1.w = f2bf(v1.w - bf2f(h1.w));
    unsigned short* base = xfrag +
        ((size_t)(((size_t)t * 32 + k16x) * 4 + cg) * 2) * 512 + lane * 8;
    *(ushort4*)(base)           = h0;
    *(ushort4*)(base + 4)       = h1;
    *(ushort4*)(base + 512)     = l0;
    *(ushort4*)(base + 512 + 4) = l1;
}

// Prep 3: c copy; h0 (H,B) -> hfrag0. 512 blocks x 256.
__global__ void prep_state(const float* __restrict__ cin, const float* __restrict__ hin,
                           float* __restrict__ cdst, unsigned short* __restrict__ hfrag0)
{
    const int idx = blockIdx.x * 256 + threadIdx.x;   // 0..131071
    cdst[idx] = cin[idx];
    const int j = idx >> 7;
    const int b = idx & 127;
    float f = hin[idx];
    unsigned short hh = f2bf(f);
    unsigned short hl = f2bf(f - bf2f(hh));
    const int k16h = j >> 4;
    const int hlf  = (j >> 3) & 1;
    const int e    = j & 7;
    const int cg   = b >> 5;
    const int lane = 32 * hlf + (b & 31);
    unsigned short* base = hfrag0 +
        ((size_t)((k16h * 4 + cg) * 2) * 512) + lane * 8 + e;
    base[0]   = hh;
    base[512] = hl;
}

// ---------------------------------------------------------------------------
// z0 chunk GEMM: z0[t][.] = Wx . x_t + b for t in [tbase, tbase+32).
// Grid (s:128, tq:32) x 512 thr. Block: 32 gate-rows x 128 cols, K=512.
// Waves: cw = wv&1 (cg pair 2cw,2cw+1), kq = wv>>1 (k16 = 4m+kq, m=0..7).
// Split-bf16 triple product, 2 chains/col-tile. Partials via 2-stage LDS.
// launch_bounds (512,2): grid is 16 blocks/CU deep, co-residency > VGPRs here.
// ---------------------------------------------------------------------------
__global__ __launch_bounds__(512, 2) void gemm_z0(
    const unsigned short* __restrict__ wfrag,
    const unsigned short* __restrict__ xfrag,
    float* __restrict__ z0,
    const float* __restrict__ bg, const float* __restrict__ bi,
    const float* __restrict__ bf_, const float* __restrict__ bo,
    int tbase)
{
    const int tid  = threadIdx.x;
    const int wv   = tid >> 6;
    const int lane = tid & 63;
    const int l31  = lane & 31;
    const int hl   = lane >> 5;
    const int cw   = wv & 1;
    const int kq   = wv >> 1;              // 0..3
    const int s    = blockIdx.x;           // 0..127
    const int t    = tbase + blockIdx.y;   // timestep
    const int tslot = t & (ZSLOTS - 1);

    // A: k16 = 4m + kq
    const unsigned short* pA = wfrag + ((size_t)(s * NK16 + kq) * 2) * 512 + lane * 8;
    // B: xfrag[t][k16][cg][p][512]; tiles cg = 2cw, 2cw+1
    const unsigned short* pB = xfrag + (size_t)t * 131072
                             + (size_t)(4 * kq + 2 * cw) * 1024 + lane * 8;

    f32x16 a0A, a0B, a1A, a1B;   // tile0/tile1, chains A=(Ah+Al)*Bh, B=Ah*Bl
#pragma unroll
    for (int r = 0; r < 16; ++r) { a0A[r]=0.f; a0B[r]=0.f; a1A[r]=0.f; a1B[r]=0.f; }

#pragma unroll
    for (int m = 0; m < 8; ++m) {
        short8 Ah  = LD8(pA);
        short8 Al  = LD8(pA + 512);
        short8 B0h = LD8(pB);
        short8 B0l = LD8(pB + 512);
        short8 B1h = LD8(pB + 1024);
        short8 B1l = LD8(pB + 1536);
        pA += 4096; pB += 16384;
        a0A = MFMA32(Ah, B0h, a0A);
        a1A = MFMA32(Ah, B1h, a1A);
        a0B = MFMA32(Ah, B0l, a0B);
        a1B = MFMA32(Ah, B1l, a1B);
        a0A = MFMA32(Al, B0h, a0A);
        a1A = MFMA32(Al, B1h, a1A);
    }

    __shared__ float part[2][32][128];     // 32 KB

    // stage 1: kq 2,3 dump; stage 2: kq 0,1 add.
    if (kq >= 2) {
#pragma unroll
        for (int r = 0; r < 16; ++r) {
            const int lr = (r & 3) + 8 * (r >> 2) + 4 * hl;
            part[kq - 2][lr][(2 * cw)     * 32 + l31] = a0A[r] + a0B[r];
            part[kq - 2][lr][(2 * cw + 1) * 32 + l31] = a1A[r] + a1B[r];
        }
    }
    __syncthreads();
    if (kq < 2) {
#pragma unroll
        for (int r = 0; r < 16; ++r) {
            const int lr = (r & 3) + 8 * (r >> 2) + 4 * hl;
            part[kq][lr][(2 * cw)     * 32 + l31] += a0A[r] + a0B[r];
            part[kq][lr][(2 * cw + 1) * 32 + l31] += a1A[r] + a1B[r];
        }
    }
    __syncthreads();

    // final: thread (lr = tid>>4, c0 = (tid&15)*8): z = p0+p1 + bias -> z0
    {
        const int lr = tid >> 4;
        const int c0 = (tid & 15) * 8;
        const int g  = lr & 3;
        const int j  = s * 8 + (lr >> 2);
        const float bb = (g == 0 ? bg : g == 1 ? bi : g == 2 ? bf_ : bo)[j];
        float z[8];
#pragma unroll
        for (int cc = 0; cc < 8; ++cc)
            z[cc] = part[0][lr][c0 + cc] + part[1][lr][c0 + cc] + bb;
        float* dst = z0 + (((size_t)tslot * 128 + s) * 32 + lr) * 128 + c0;
        *(float4*)(dst)     = make_float4(z[0], z[1], z[2], z[3]);
        *(float4*)(dst + 4) = make_float4(z[4], z[5], z[6], z[7]);
    }
}

// ---------------------------------------------------------------------------
// One LSTM timestep. Grid 256 x 512 (8 waves), 1 block/CU.
// XCD swizzle: xcd = bx&7 owns rowslices xcd*16..+15 (weight slice stays
// XCD-L2-resident across launches). Block: 32 gate-rows (8 j) x 64 cols.
// Waves = 8 pure K-slices (k16 = 8m + wv) covering BOTH 32-col tiles.
// Round-8 tail trim: SINGLE-stage LDS reduction (64 KB part, one sync) and
// DIRECT fragment-layout h scatter from gate threads (no LDS transpose, no
// second/third barrier). All LDS access patterns are 2-way on 32 banks = free.
// ---------------------------------------------------------------------------
__global__ __launch_bounds__(512, 1) void lstm_step(
    const unsigned short* __restrict__ wfrag,
    const unsigned short* __restrict__ xfrag,
    const float* __restrict__ z0,
    const unsigned short* __restrict__ hin,
    unsigned short* __restrict__ hout,
    float* __restrict__ cst,
    const float* __restrict__ bg, const float* __restrict__ bi,
    const float* __restrict__ bf_, const float* __restrict__ bo,
    float* __restrict__ outf, int t)
{
    const int tid  = threadIdx.x;
    const int wv   = tid >> 6;             // K-slice 0..7
    const int lane = tid & 63;
    const int l31  = lane & 31;
    const int hl   = lane >> 5;
    const int bx   = blockIdx.x;

    const int xcd     = bx & 7;
    const int ii      = bx >> 3;
    const int s       = xcd * 16 + (ii >> 1);   // rowslice 0..127
    const int cb      = ii & 1;                 // col half
    const int colbase = cb << 6;
    const int J0      = s * 8;

    // epilogue role: thread = (jloc = tid>>6, cl = tid&63)
    const int ejl  = tid >> 6;
    const int ecl  = tid & 63;
    const int ej   = J0 + ejl;
    const int ecol = colbase + ecl;

    // preload additive terms + c (hides latency under K-loop)
    float add0, add1, add2, add3;
    if (z0) {
        const float* zp = z0 + (((size_t)(t & (ZSLOTS - 1)) * 128 + s) * 32
                                + 4 * ejl) * 128 + ecol;
        add0 = zp[0]; add1 = zp[128]; add2 = zp[256]; add3 = zp[384];
    } else {
        add0 = bg[ej]; add1 = bi[ej]; add2 = bf_[ej]; add3 = bo[ej];
    }
    const size_t ci = (size_t)ej * BATCH + ecol;
    float cold = cst[ci];

    f32x16 a0A, a0B, a1A, a1B;   // tile0/tile1 (cols 0-31 / 32-63 of block)
#pragma unroll
    for (int r = 0; r < 16; ++r) { a0A[r]=0.f; a0B[r]=0.f; a1A[r]=0.f; a1B[r]=0.f; }

    // B tile base offsets in act fragments: cg = 2*cb + tile
    const size_t bOff = (size_t)(4 * wv + 2 * cb) * 1024 + lane * 8;

    if (z0) {
        // h-only: k16h = 8m + wv, m = 0..7
        const unsigned short* pA = wfrag + ((size_t)(s * NK16 + 32 + wv) * 2) * 512 + lane * 8;
        const unsigned short* pH = hin + bOff;
#pragma unroll
        for (int m = 0; m < 8; ++m) {
            short8 Ah  = LD8(pA);
            short8 Al  = LD8(pA + 512);
            short8 B0h = LD8(pH);
            short8 B0l = LD8(pH + 512);
            short8 B1h = LD8(pH + 1024);
            short8 B1l = LD8(pH + 1536);
            pA += 8192; pH += 32768;
            a0A = MFMA32(Ah, B0h, a0A);
            a1A = MFMA32(Ah, B1h, a1A);
            a0B = MFMA32(Ah, B0l, a0B);
            a1B = MFMA32(Ah, B1l, a1B);
            a0A = MFMA32(Al, B0h, a0A);
            a1A = MFMA32(Al, B1h, a1A);
        }
    } else {
        // full K: k16 = 8m + wv, m=0..3 x-part, m=4..11 h-part
        const unsigned short* pA = wfrag + ((size_t)(s * NK16 + wv) * 2) * 512 + lane * 8;
        const unsigned short* pX = xfrag + (size_t)t * 131072 + bOff;
#pragma unroll
        for (int m = 0; m < 4; ++m) {
            short8 Ah  = LD8(pA);
            short8 Al  = LD8(pA + 512);
            short8 B0h = LD8(pX);
            short8 B0l = LD8(pX + 512);
            short8 B1h = LD8(pX + 1024);
            short8 B1l = LD8(pX + 1536);
            pA += 8192; pX += 32768;
            a0A = MFMA32(Ah, B0h, a0A);
            a1A = MFMA32(Ah, B1h, a1A);
            a0B = MFMA32(Ah, B0l, a0B);
            a1B = MFMA32(Ah, B1l, a1B);
            a0A = MFMA32(Al, B0h, a0A);
            a1A = MFMA32(Al, B1h, a1A);
        }
        const unsigned short* pH = hin + bOff;
#pragma unroll
        for (int m = 0; m < 8; ++m) {
            short8 Ah  = LD8(pA);
            short8 Al  = LD8(pA + 512);
            short8 B0h = LD8(pH);
            short8 B0l = LD8(pH + 512);
            short8 B1h = LD8(pH + 1024);
            short8 B1l = LD8(pH + 1536);
            pA += 8192; pH += 32768;
            a0A = MFMA32(Ah, B0h, a0A);
            a1A = MFMA32(Ah, B1h, a1A);
            a0B = MFMA32(Ah, B0l, a0B);
            a1B = MFMA32(Ah, B1l, a1B);
            a0A = MFMA32(Al, B0h, a0A);
            a1A = MFMA32(Al, B1h, a1A);
        }
    }

    // single-stage K-partial dump: all 8 waves, one barrier.
    // D layout (verified): localrow = (r&3) + 8*(r>>2) + 4*hl, col = l31.
    __shared__ float part[8][32][64];          // 64 KB
#pragma unroll
    for (int r = 0; r < 16; ++r) {
        const int lr = (r & 3) + 8 * (r >> 2) + 4 * hl;
        part[wv][lr][l31]      = a0A[r] + a0B[r];
        part[wv][lr][32 + l31] = a1A[r] + a1B[r];
    }
    __syncthreads();

    // gates: thread (ejl, ecl); sum 8 K-partials per gate.
    {
        const int r0 = 4 * ejl;
        float z0g = add0, z1g = add1, z2g = add2, z3g = add3;
#pragma unroll
        for (int p = 0; p < 8; ++p) {
            z0g += part[p][r0 + 0][ecl];
            z1g += part[p][r0 + 1][ecl];
            z2g += part[p][r0 + 2][ecl];
            z3g += part[p][r0 + 3][ecl];
        }
        float gg = tanh_f(z0g);
        float ig = sigmoid_f(z1g);
        float fg = sigmoid_f(z2g);
        float og = sigmoid_f(z3g);
        float cn = gg * ig + cold * fg;
        cst[ci] = cn;
        float hh = tanh_f(cn) * og;
        unsigned short hb  = f2bf(hh);
        unsigned short hlo = f2bf(hh - bf2f(hb));
        // direct h scatter in fragment layout (matches prep_state mapping):
        // j = s*8+ejl -> k16h = s>>1, hlf = s&1, e = ejl; col -> cg, lane.
        const int k16h  = s >> 1;
        const int cgg   = (colbase >> 5) + (ecl >> 5);
        const int lane8 = 32 * (s & 1) + (ecl & 31);
        unsigned short* dst = hout +
            ((size_t)((k16h * 4 + cgg) * 2) * 512) + lane8 * 8 + ejl;
        dst[0]   = hb;
        dst[512] = hlo;
        if (outf) outf[ci] = hh;
    }
}

// ---------------------------------------------------------------------------
extern "C" void kernel_launch(void* const* d_in, const int* in_sizes, int n_in,
                              void* d_out, int out_size, void* d_ws, size_t ws_size,
                              hipStream_t stream)
{
    const float* x   = (const float*)d_in[0];
    const float* c0v = (const float*)d_in[1];
    const float* h0v = (const float*)d_in[2];
    const float* Wgx = (const float*)d_in[3];
    const float* Wix = (const float*)d_in[4];
    const float* Wfx = (const float*)d_in[5];
    const float* Wox = (const float*)d_in[6];
    const float* Wgh = (const float*)d_in[7];
    const float* Wih = (const float*)d_in[8];
    const float* Wfh = (const float*)d_in[9];
    const float* Woh = (const float*)d_in[10];
    const float* bg  = (const float*)d_in[11];
    const float* bi  = (const float*)d_in[12];
    const float* bf  = (const float*)d_in[13];
    const float* bo  = (const float*)d_in[14];

    // ws layout (ushort unless noted):
    //   wfrag 25.2 MB | xfrag 67.1 MB | hf0,hf1 0.5 MB ea | cst 0.5 MB
    //   z0 64 MB (f32, only if ws_size permits)  => mode-A total ~161 MB
    unsigned short* wfrag = (unsigned short*)d_ws;
    unsigned short* xfrag = wfrag + (size_t)128 * NK16 * 2 * 512;
    unsigned short* hf0   = xfrag + (size_t)TSTEPS * 32 * 4 * 2 * 512;
    unsigned short* hf1   = hf0 + (size_t)64 * 4 * 2 * 512;
    float* cst            = (float*)(hf1 + (size_t)64 * 4 * 2 * 512);
    float* z0             = (float*)(cst + (size_t)HID * BATCH);

    const size_t needA = (size_t)((char*)(z0 + (size_t)ZSLOTS * 4096 * 128) - (char*)d_ws);
    const bool useA = (ws_size >= needA);

    unsigned short* hf[2] = { hf0, hf1 };
    float* outp = (float*)d_out;

    prep_w<<<dim3(NK16, 128), dim3(256), 0, stream>>>(Wgx, Wix, Wfx, Wox,
                                                      Wgh, Wih, Wfh, Woh, wfrag);
    prep_x<<<dim3(32, TSTEPS), dim3(256), 0, stream>>>(x, xfrag);
    prep_state<<<dim3(512), dim3(256), 0, stream>>>(c0v, h0v, cst, hf[0]);

    if (useA) {
        for (int q = 0; q < TSTEPS / ZSLOTS; ++q) {
            gemm_z0<<<dim3(128, ZSLOTS), dim3(512), 0, stream>>>(
                wfrag, xfrag, z0, bg, bi, bf, bo, q * ZSLOTS);
            for (int tt = 0; tt < ZSLOTS; ++tt) {
                const int t = q * ZSLOTS + tt;
                lstm_step<<<dim3(256), dim3(512), 0, stream>>>(
                    wfrag, xfrag, z0, hf[t & 1], hf[(t + 1) & 1],
                    cst, bg, bi, bf, bo,
                    (t == TSTEPS - 1) ? outp : nullptr, t);
            }
        }
    } else {
        for (int t = 0; t < TSTEPS; ++t) {
            lstm_step<<<dim3(256), dim3(512), 0, stream>>>(
                wfrag, xfrag, nullptr, hf[t & 1], hf[(t + 1) & 1],
                cst, bg, bi, bf, bo,
                (t == TSTEPS - 1) ? outp : nullptr, t);
        }
    }
}